// Round 4
// baseline (75.121 us; speedup 1.0000x reference)
//
#include <hip/hip_runtime.h>

// Problem constants (fixed by setup_inputs in the reference):
//   candidate_pts (2,128,10,3) -> queries (B=2, S=1280, 3)
//   src_keypts    (2,128,3)    -> UNUSED by reference
//   tgt_pts_xyz   (2,16384,3)
//   tgt_deep_feat (2,16384,32)
// out (2,128,10,32,35) fp32 = (B, S, K=32, 3+F)
constexpr int B_  = 2;
constexpr int S_  = 1280;     // 128 * 10
constexpr int N_  = 16384;
constexpr int F_  = 32;
constexpr int K_  = 32;
constexpr int CH_ = 3 + F_;   // 35
constexpr float R2_ = 4.0f;   // D_RADIUS^2

// NOTE: HIP float3 is ext_vector_type(3): sizeof==16, alignof==16 — NOT the
// CUDA 12/4. Loading packed (x,y,z) triplets through it would over-read 4 B
// (OOB at the last point) and lie about alignment. Use a packed struct whose
// load lowers to global_load_dwordx3 (exactly 12 B, 4 B-aligned).
struct f3 { float x, y, z; };
static_assert(sizeof(f3) == 12 && alignof(f3) == 4, "f3 must be packed");

// 4 waves per query: each round speculatively scans 4*512 = 2048 points in
// parallel (wave w owns the 512-point span starting at round*2048 + w*512),
// then combines per-wave ballot counts through LDS to assign first-K slots in
// global index order. Typical query (42% in-radius) finishes in ONE round;
// only ~0.1% of queries (far from origin) take a second.
constexpr int WPB  = 4;                 // waves per block
constexpr int CPW  = 8;                 // 64-pt chunks per wave per round
constexpr int RPTS = WPB * CPW * 64;    // 2048 points per round
constexpr int NR   = N_ / RPTS;         // 8 rounds max

__global__ __launch_bounds__(256) void ballquery_gather(
    const float* __restrict__ cand,   // (B,S,3)
    const float* __restrict__ xyz,    // (B,N,3)
    const float* __restrict__ feat,   // (B,N,F)
    float* __restrict__ out)          // (B,S,K,CH)
{
    const int q    = blockIdx.x;        // 0 .. B*S-1
    const int b    = q / S_;
    const int tid  = threadIdx.x;       // 0 .. 255
    const int lane = tid & 63;
    const int wave = tid >> 6;          // 0 .. 3

    const float qx = cand[q * 3 + 0];
    const float qy = cand[q * 3 + 1];
    const float qz = cand[q * 3 + 2];
    // Replicate reference op order exactly; _rn intrinsics forbid FMA fusion.
    const float qq = __fadd_rn(__fadd_rn(__fmul_rn(qx, qx), __fmul_rn(qy, qy)),
                               __fmul_rn(qz, qz));

    const float* __restrict__ xb = xyz  + (size_t)b * N_ * 3;
    const float* __restrict__ fb = feat + (size_t)b * N_ * F_;

    __shared__ int sidx[K_];
    __shared__ int scnt[WPB];

    int found = 0;  // block-uniform running count of in-radius points

    for (int r = 0; r < NR; ++r) {
        const int base = (r * WPB + wave) * (CPW * 64);

        // Each lane loads its point's 12 B as one dwordx3: 8 load instrs per
        // wave-round instead of 24; the wave's 768 B footprint is fully
        // consumed (no cacheline over-touch).
        float px[CPW], py[CPW], pz[CPW];
        #pragma unroll
        for (int c = 0; c < CPW; ++c) {
            const int n = base + c * 64 + lane;    // always < N_
            const f3 p = *reinterpret_cast<const f3*>(xb + (size_t)n * 3);
            px[c] = p.x;
            py[c] = p.y;
            pz[c] = p.z;
        }

        // Ballot each chunk; masks are wave-uniform (live in SGPRs).
        unsigned long long m[CPW];
        int cnt = 0;
        #pragma unroll
        for (int c = 0; c < CPW; ++c) {
            const float x0 = px[c], x1 = py[c], x2 = pz[c];
            const float dot = __fadd_rn(__fadd_rn(__fmul_rn(qx, x0), __fmul_rn(qy, x1)),
                                        __fmul_rn(qz, x2));
            const float xx  = __fadd_rn(__fadd_rn(__fmul_rn(x0, x0), __fmul_rn(x1, x1)),
                                        __fmul_rn(x2, x2));
            // sqr = (qq - 2*dot) + xx   (matches  sum1 - 2*einsum + sum2)
            const float sqr = __fadd_rn(__fsub_rn(qq, __fmul_rn(2.0f, dot)), xx);
            const bool pred = !(sqr > R2_);   // kept iff sqr <= R2 (NaN-keeping)
            m[c] = __ballot(pred);
            cnt += __popcll(m[c]);
        }

        if (lane == 0) scnt[wave] = cnt;
        __syncthreads();

        // Cross-wave exclusive prefix (4 entries — cheap) + round total.
        int prefix = found;
        int total  = 0;
        #pragma unroll
        for (int w = 0; w < WPB; ++w) {
            const int cw = scnt[w];
            if (w < wave) prefix += cw;
            total += cw;
        }

        // Scatter this wave's in-radius indices into global-index-ordered slots.
        if (prefix < K_) {
            int slot = prefix;
            #pragma unroll
            for (int c = 0; c < CPW; ++c) {
                const unsigned long long mm = m[c];
                const int p = __popcll(mm & ((1ull << lane) - 1ull));
                if (((mm >> lane) & 1ull) && (slot + p) < K_)
                    sidx[slot + p] = base + c * 64 + lane;
                slot += __popcll(mm);
            }
        }

        found += total;
        __syncthreads();   // sidx visible; scnt reusable next round
        if (found >= K_) break;   // block-uniform
    }

    // Pad trailing slots with the first neighbor (reference semantics).
    // found==0 can't happen with this data; JAX OOB-gather clamps N -> N-1.
    const int first = (found > 0) ? sidx[0] : (N_ - 1);
    if (tid < K_ && tid >= found)
        sidx[tid] = first;
    __syncthreads();

    float* __restrict__ ob = out + (size_t)q * (K_ * CH_);

    // Features: 32 neighbors x 8 threads, each one float4 (128 B contiguous
    // per neighbor row -> coalesced L2 gathers).
    {
        const int k = tid >> 3;          // 0..31
        const int j = tid & 7;           // 0..7
        const int n = sidx[k];
        const float4 v = *reinterpret_cast<const float4*>(fb + (size_t)n * F_ + j * 4);
        float* o = ob + k * CH_ + 3 + j * 4;
        o[0] = v.x; o[1] = v.y; o[2] = v.z; o[3] = v.w;
    }
    // xyz / D_RADIUS: 96 threads, one component each.
    if (tid < K_ * 3) {
        const int kk = tid / 3;
        const int c  = tid - kk * 3;
        ob[kk * CH_ + c] = xb[sidx[kk] * 3 + c] * 0.5f;
    }
}

extern "C" void kernel_launch(void* const* d_in, const int* in_sizes, int n_in,
                              void* d_out, int out_size, void* d_ws, size_t ws_size,
                              hipStream_t stream) {
    const float* cand = (const float*)d_in[0];   // candidate_pts
    // d_in[1] = src_keypts — unused by the reference
    const float* xyz  = (const float*)d_in[2];   // tgt_pts_xyz
    const float* feat = (const float*)d_in[3];   // tgt_deep_feat_pts
    float* out = (float*)d_out;

    ballquery_gather<<<B_ * S_, 256, 0, stream>>>(cand, xyz, feat, out);
}